// Round 7
// baseline (26.452 us; speedup 1.0000x reference)
//
#include <hip/hip_runtime.h>

// SparseNodeLinear, two-phase sparse:
//   out[b,f,n] = sum_{k: em[n,k]==0} x[b,k,n] * w[n,k,f] + bias[f,n]
// x: [B,K,N] f32, w: [N,K,F] f32, bias: [F,N] f32, em: [N,K] int32, out: [B,F,N] f32
// B=8, N=2048, K=2049, F=32.  ~34 active k per node.
//
// Phase 1 (scan): stream em at full BW, emit compact per-node k-lists to d_ws.
// Phase 2 (main): per node, read the tiny list (L2-local via matching XCD swizzle),
// gather x + preload w immediately (2-deep chain), FMA, reduce, store.

constexpr int N_ = 2048;
constexpr int K_ = 2049;
constexpr int F_ = 32;
constexpr int B_ = 8;
constexpr int CH = 9;      // ceil(K/256)
constexpr int LCAP = 96;   // per-node active cap (mean ~34, sigma ~5.6; 11-sigma margin)

__device__ __forceinline__ int swz(int bid) {       // XCD-contiguous n chunks
    return ((bid & 7) << 8) | (bid >> 3);
}

// ---------------- phase 1: em scan -> compact lists ----------------
__global__ __launch_bounds__(256, 8) void snl_scan(
    const int* __restrict__ em, int* __restrict__ cnt, int* __restrict__ list)
{
    const int n    = swz(blockIdx.x);
    const int t    = threadIdx.x;
    const int lane = t & 63;
    const int wid  = t >> 6;

    __shared__ int s_cnt[CH * 4];
    const int* emn = em + (size_t)n * K_;

    int emr[CH];
    #pragma unroll
    for (int c = 0; c < CH - 1; ++c) emr[c] = emn[c * 256 + t];
    emr[CH - 1] = (t == 0) ? emn[2048] : 1;

    const unsigned long long lowmask = (1ull << lane) - 1ull;
    int woff[CH];
    unsigned actmask = 0;
    #pragma unroll
    for (int c = 0; c < CH; ++c) {
        const unsigned long long bal = __ballot(emr[c] == 0);
        if (lane == 0) s_cnt[c * 4 + wid] = __popcll(bal);
        woff[c] = __popcll(bal & lowmask);
        actmask |= (emr[c] == 0 ? 1u : 0u) << c;
    }
    __syncthreads();

    int ct = 0;
    int* ln = list + (size_t)n * LCAP;
    #pragma unroll
    for (int c = 0; c < CH; ++c) {
        const int c0 = s_cnt[c * 4 + 0];
        const int c1 = s_cnt[c * 4 + 1];
        const int c2 = s_cnt[c * 4 + 2];
        const int c3 = s_cnt[c * 4 + 3];
        const int base = ct + ((wid > 0) ? c0 : 0) + ((wid > 1) ? c1 : 0) + ((wid > 2) ? c2 : 0);
        ct += c0 + c1 + c2 + c3;
        if ((actmask >> c) & 1u) {
            const int pos = base + woff[c];
            if (pos < LCAP) ln[pos] = c * 256 + t;
        }
    }
    if (t == 0) cnt[n] = (ct < LCAP) ? ct : LCAP;
}

// ---------------- phase 2: gather + FMA ----------------
__global__ __launch_bounds__(256, 8) void snl_main(
    const float* __restrict__ x,
    const float* __restrict__ w,
    const float* __restrict__ bias,
    const int*   __restrict__ cnt,
    const int*   __restrict__ list,
    float* __restrict__ out)
{
    const int n = swz(blockIdx.x);
    const int t = threadIdx.x;
    const int p = t >> 5;    // 0..7 : slot phase
    const int f = t & 31;

    __shared__ float s_x[LCAP][B_];
    __shared__ float s_red[8][B_][F_];

    const int* ln = list + (size_t)n * LCAP;
    const int  ct = cnt[n];                       // broadcast load
    const float bv = bias[(size_t)(t & 31) * N_ + n];   // epilogue bias, prefetched

    // x gather: thread (slot, b), 3 rounds cover LCAP=96
    {
        const int slot0 = t >> 3;   // 0..31
        const int gb    = t & 7;
        #pragma unroll
        for (int r = 0; r < 3; ++r) {
            const int s = slot0 + 32 * r;
            if (s < ct) {
                const int k = ln[s];
                s_x[s][gb] = x[((size_t)gb * K_ + k) * N_ + n];
            }
        }
    }

    // w preload (independent of x gather; both in flight)
    const float* wn = w + (size_t)n * K_ * F_;
    float wr[12];
    #pragma unroll
    for (int i = 0; i < 12; ++i) {
        const int s = p + 8 * i;
        if (s < ct) wr[i] = wn[(size_t)ln[s] * F_ + f];
    }

    __syncthreads();

    float acc[B_];
    #pragma unroll
    for (int b = 0; b < B_; ++b) acc[b] = 0.f;

    #pragma unroll
    for (int i = 0; i < 12; ++i) {
        const int s = p + 8 * i;
        if (s < ct) {
            const float4 x0 = *reinterpret_cast<const float4*>(&s_x[s][0]);
            const float4 x1 = *reinterpret_cast<const float4*>(&s_x[s][4]);
            const float wv = wr[i];
            acc[0] = fmaf(x0.x, wv, acc[0]);
            acc[1] = fmaf(x0.y, wv, acc[1]);
            acc[2] = fmaf(x0.z, wv, acc[2]);
            acc[3] = fmaf(x0.w, wv, acc[3]);
            acc[4] = fmaf(x1.x, wv, acc[4]);
            acc[5] = fmaf(x1.y, wv, acc[5]);
            acc[6] = fmaf(x1.z, wv, acc[6]);
            acc[7] = fmaf(x1.w, wv, acc[7]);
        }
    }

    #pragma unroll
    for (int b = 0; b < B_; ++b) s_red[p][b][f] = acc[b];
    __syncthreads();

    {
        const int b  = t >> 5;
        const int ff = t & 31;
        float s = 0.f;
        #pragma unroll
        for (int q = 0; q < 8; ++q) s += s_red[q][b][ff];
        out[((size_t)b * F_ + ff) * N_ + n] = s + bv;
    }
}

// ---------------- fallback: proven R6 single-kernel path ----------------
constexpr int WCAP = 48;

__global__ __launch_bounds__(256, 8) void snl_sparse3(
    const float* __restrict__ x,
    const float* __restrict__ w,
    const float* __restrict__ bias,
    const int*   __restrict__ em,
    float* __restrict__ out)
{
    const int bid  = blockIdx.x;
    const int n    = swz(bid);
    const int t    = threadIdx.x;
    const int lane = t & 63;
    const int wid  = t >> 6;

    __shared__ int   s_idx[4][WCAP];
    __shared__ float s_x[4][WCAP][B_];
    __shared__ float s_red[8][B_][F_];

    const int*   emn = em + (size_t)n * K_;
    const float* wn  = w  + (size_t)n * K_ * F_;

    int emr[CH];
    #pragma unroll
    for (int c = 0; c < CH - 1; ++c) emr[c] = emn[c * 256 + t];
    emr[CH - 1] = (t == 0) ? emn[2048] : 1;

    const unsigned long long lowmask = (1ull << lane) - 1ull;
    int wcnt = 0;
    #pragma unroll
    for (int c = 0; c < CH; ++c) {
        const bool act = (emr[c] == 0);
        const unsigned long long bal = __ballot(act);
        const int pos = wcnt + __popcll(bal & lowmask);
        wcnt += __popcll(bal);
        if (act && pos < WCAP) s_idx[wid][pos] = c * 256 + t;
    }
    wcnt = (wcnt < WCAP) ? wcnt : WCAP;
    const int wcnt_p = (wcnt + 1) & ~1;
    if (lane == 0 && (wcnt & 1)) s_idx[wid][wcnt] = 0;

    {
        const int slot0 = lane >> 3;
        const int gb    = lane & 7;
        #pragma unroll
        for (int r = 0; r < 2; ++r) {
            const int slot = slot0 + r * 8;
            if (slot < wcnt_p) {
                float xv = 0.f;
                if (slot < wcnt) xv = x[((size_t)gb * K_ + s_idx[wid][slot]) * N_ + n];
                s_x[wid][slot][gb] = xv;
            }
        }
        for (int slot = slot0 + 16; slot < wcnt_p; slot += 8) {
            float xv = 0.f;
            if (slot < wcnt) xv = x[((size_t)gb * K_ + s_idx[wid][slot]) * N_ + n];
            s_x[wid][slot][gb] = xv;
        }
    }

    const int kp2 = lane >> 5;
    const int f   = lane & 31;
    const int tc  = wcnt_p >> 1;
    float wr[8];
    #pragma unroll
    for (int i = 0; i < 8; ++i)
        if (i < tc) wr[i] = wn[(size_t)s_idx[wid][kp2 + 2 * i] * F_ + f];

    float acc[B_];
    #pragma unroll
    for (int b = 0; b < B_; ++b) acc[b] = 0.f;

    #pragma unroll
    for (int i = 0; i < 8; ++i) {
        if (i < tc) {
            const int slot = kp2 + 2 * i;
            const float4 x0 = *reinterpret_cast<const float4*>(&s_x[wid][slot][0]);
            const float4 x1 = *reinterpret_cast<const float4*>(&s_x[wid][slot][4]);
            const float wv = wr[i];
            acc[0] = fmaf(x0.x, wv, acc[0]);
            acc[1] = fmaf(x0.y, wv, acc[1]);
            acc[2] = fmaf(x0.z, wv, acc[2]);
            acc[3] = fmaf(x0.w, wv, acc[3]);
            acc[4] = fmaf(x1.x, wv, acc[4]);
            acc[5] = fmaf(x1.y, wv, acc[5]);
            acc[6] = fmaf(x1.z, wv, acc[6]);
            acc[7] = fmaf(x1.w, wv, acc[7]);
        }
    }
    for (int slot = kp2 + 16; slot < wcnt_p; slot += 2) {
        const float wv = wn[(size_t)s_idx[wid][slot] * F_ + f];
        const float4 x0 = *reinterpret_cast<const float4*>(&s_x[wid][slot][0]);
        const float4 x1 = *reinterpret_cast<const float4*>(&s_x[wid][slot][4]);
        acc[0] = fmaf(x0.x, wv, acc[0]);
        acc[1] = fmaf(x0.y, wv, acc[1]);
        acc[2] = fmaf(x0.z, wv, acc[2]);
        acc[3] = fmaf(x0.w, wv, acc[3]);
        acc[4] = fmaf(x1.x, wv, acc[4]);
        acc[5] = fmaf(x1.y, wv, acc[5]);
        acc[6] = fmaf(x1.z, wv, acc[6]);
        acc[7] = fmaf(x1.w, wv, acc[7]);
    }

    #pragma unroll
    for (int b = 0; b < B_; ++b) s_red[wid * 2 + kp2][b][f] = acc[b];
    __syncthreads();

    {
        const int b  = t >> 5;
        const int ff = t & 31;
        float s = 0.f;
        #pragma unroll
        for (int q = 0; q < 8; ++q) s += s_red[q][b][ff];
        out[((size_t)b * F_ + ff) * N_ + n] = s + bias[(size_t)ff * N_ + n];
    }
}

extern "C" void kernel_launch(void* const* d_in, const int* in_sizes, int n_in,
                              void* d_out, int out_size, void* d_ws, size_t ws_size,
                              hipStream_t stream) {
    const float* x    = (const float*)d_in[0];
    const float* w    = (const float*)d_in[1];
    const float* bias = (const float*)d_in[2];
    const int*   em   = (const int*)d_in[3];
    float*       out  = (float*)d_out;

    const size_t need = sizeof(int) * ((size_t)N_ + (size_t)N_ * LCAP);
    if (ws_size >= need) {
        int* cnt  = (int*)d_ws;
        int* list = cnt + N_;
        snl_scan<<<dim3(N_), dim3(256), 0, stream>>>(em, cnt, list);
        snl_main<<<dim3(N_), dim3(256), 0, stream>>>(x, w, bias, cnt, list, out);
    } else {
        snl_sparse3<<<dim3(N_), dim3(256), 0, stream>>>(x, w, bias, em, out);
    }
}

// Round 8
// 20.687 us; speedup vs baseline: 1.2787x; 1.2787x over previous
//
#include <hip/hip_runtime.h>

// SparseNodeLinear, wave-autonomous + n-quad blocking:
//   out[b,f,n] = sum_{k: em[n,k]==0} x[b,k,n] * w[n,k,f] + bias[f,n]
// x: [B,K,N] f32, w: [N,K,F] f32, bias: [F,N] f32, em: [N,K] int32, out: [B,F,N] f32
// B=8, N=2048, K=2049, F=32.  ~34 active k per node (~8.5 per wave).
//
// 512 blocks x 1024 threads. Each block = 4 sub-blocks of 256 threads; sub-block
// g handles node n0+g with the proven R6 wave-autonomous pipeline (ballot ->
// wave-local list -> full-wave x gather || w preload -> FMA). The epilogue is
// transposed: thread (b,f) reduces all 4 nodes and writes ONE float4 (and reads
// float4 bias) -> kills the 4B-at-8KB-stride sector inflation (~29 MB saved).

constexpr int N_ = 2048;
constexpr int K_ = 2049;
constexpr int F_ = 32;
constexpr int B_ = 8;
constexpr int CH = 9;     // ceil(K/256)
constexpr int WCAP = 48;  // per-wave active cap (mean 8.5, sigma 2.9)
constexpr int G_ = 4;     // nodes per block

__global__ __launch_bounds__(1024, 8) void snl_sparse4(
    const float* __restrict__ x,
    const float* __restrict__ w,
    const float* __restrict__ bias,
    const int*   __restrict__ em,
    float* __restrict__ out)
{
    const int gid = blockIdx.x;                       // 0..511
    const int sg  = ((gid & 7) << 6) | (gid >> 3);    // XCD-contiguous group chunks
    const int n0  = sg * G_;

    const int t    = threadIdx.x;        // 0..1023
    const int g4   = t >> 8;             // sub-block 0..3
    const int ts   = t & 255;            // index within sub-block
    const int lane = t & 63;
    const int wid  = (t >> 6) & 3;       // wave within sub-block

    const int n = n0 + g4;

    __shared__ int   s_idx[G_][4][WCAP];
    __shared__ float s_x[G_][4][WCAP][B_];
    __shared__ float s_red[G_][8][B_][F_];

    const int*   emn = em + (size_t)n * K_;
    const float* wn  = w  + (size_t)n * K_ * F_;

    // --- phase 1: 9 independent em loads ---
    int emr[CH];
    #pragma unroll
    for (int c = 0; c < CH - 1; ++c) emr[c] = emn[c * 256 + ts];
    emr[CH - 1] = (ts == 0) ? emn[2048] : 1;   // K = 2049 tail

    // --- phase 2: wave-local ballot prefix -> wave-local ordered list ---
    const unsigned long long lowmask = (1ull << lane) - 1ull;
    int wcnt = 0;
    #pragma unroll
    for (int c = 0; c < CH; ++c) {
        const bool act = (emr[c] == 0);
        const unsigned long long bal = __ballot(act);
        const int pos = wcnt + __popcll(bal & lowmask);
        wcnt += __popcll(bal);
        if (act && pos < WCAP) s_idx[g4][wid][pos] = c * 256 + ts;
    }
    wcnt = (wcnt < WCAP) ? wcnt : WCAP;
    const int wcnt_p = (wcnt + 1) & ~1;
    if (lane == 0 && (wcnt & 1)) s_idx[g4][wid][wcnt] = 0;   // pad: k=0, x zeroed below

    // --- phase 3a: full-wave x gather (wave-coherent) ---
    {
        const int slot0 = lane >> 3;   // 0..7
        const int gb    = lane & 7;    // batch
        #pragma unroll
        for (int r = 0; r < 2; ++r) {
            const int slot = slot0 + r * 8;
            if (slot < wcnt_p) {
                float xv = 0.f;
                if (slot < wcnt) xv = x[((size_t)gb * K_ + s_idx[g4][wid][slot]) * N_ + n];
                s_x[g4][wid][slot][gb] = xv;
            }
        }
        for (int slot = slot0 + 16; slot < wcnt_p; slot += 8) {   // fallback, ~never
            float xv = 0.f;
            if (slot < wcnt) xv = x[((size_t)gb * K_ + s_idx[g4][wid][slot]) * N_ + n];
            s_x[g4][wid][slot][gb] = xv;
        }
    }

    // --- phase 3b: w preload (overlapped with x gather) ---
    const int kp2 = lane >> 5;    // 0..1
    const int f   = lane & 31;
    const int tc  = wcnt_p >> 1;
    float wr[8];
    #pragma unroll
    for (int i = 0; i < 8; ++i)
        if (i < tc) wr[i] = wn[(size_t)s_idx[g4][wid][kp2 + 2 * i] * F_ + f];

    // --- phase 4: FMA over this wave's segment ---
    float acc[B_];
    #pragma unroll
    for (int b = 0; b < B_; ++b) acc[b] = 0.f;

    #pragma unroll
    for (int i = 0; i < 8; ++i) {
        if (i < tc) {
            const int slot = kp2 + 2 * i;
            const float4 x0 = *reinterpret_cast<const float4*>(&s_x[g4][wid][slot][0]);
            const float4 x1 = *reinterpret_cast<const float4*>(&s_x[g4][wid][slot][4]);
            const float wv = wr[i];
            acc[0] = fmaf(x0.x, wv, acc[0]);
            acc[1] = fmaf(x0.y, wv, acc[1]);
            acc[2] = fmaf(x0.z, wv, acc[2]);
            acc[3] = fmaf(x0.w, wv, acc[3]);
            acc[4] = fmaf(x1.x, wv, acc[4]);
            acc[5] = fmaf(x1.y, wv, acc[5]);
            acc[6] = fmaf(x1.z, wv, acc[6]);
            acc[7] = fmaf(x1.w, wv, acc[7]);
        }
    }
    for (int slot = kp2 + 16; slot < wcnt_p; slot += 2) {   // fallback, ~never
        const float wv = wn[(size_t)s_idx[g4][wid][slot] * F_ + f];
        const float4 x0 = *reinterpret_cast<const float4*>(&s_x[g4][wid][slot][0]);
        const float4 x1 = *reinterpret_cast<const float4*>(&s_x[g4][wid][slot][4]);
        acc[0] = fmaf(x0.x, wv, acc[0]);
        acc[1] = fmaf(x0.y, wv, acc[1]);
        acc[2] = fmaf(x0.z, wv, acc[2]);
        acc[3] = fmaf(x0.w, wv, acc[3]);
        acc[4] = fmaf(x1.x, wv, acc[4]);
        acc[5] = fmaf(x1.y, wv, acc[5]);
        acc[6] = fmaf(x1.z, wv, acc[6]);
        acc[7] = fmaf(x1.w, wv, acc[7]);
    }

    // --- phase 5: partials to LDS ---
    #pragma unroll
    for (int b = 0; b < B_; ++b) s_red[g4][wid * 2 + kp2][b][f] = acc[b];
    __syncthreads();

    // --- phase 6: transposed epilogue. Thread (b,f) (t<256) reduces all 4 nodes,
    //     reads float4 bias, writes ONE coalesced float4 across n0..n0+3. ---
    if (t < 256) {
        const int b  = t >> 5;
        const int ff = t & 31;
        float4 sv;
        float* s4 = reinterpret_cast<float*>(&sv);
        #pragma unroll
        for (int g = 0; g < G_; ++g) {
            float s = 0.f;
            #pragma unroll
            for (int p = 0; p < 8; ++p) s += s_red[g][p][b][ff];
            s4[g] = s;
        }
        const float4 bv = *reinterpret_cast<const float4*>(&bias[(size_t)ff * N_ + n0]);
        sv.x += bv.x; sv.y += bv.y; sv.z += bv.z; sv.w += bv.w;
        *reinterpret_cast<float4*>(&out[((size_t)b * F_ + ff) * N_ + n0]) = sv;
    }
}

extern "C" void kernel_launch(void* const* d_in, const int* in_sizes, int n_in,
                              void* d_out, int out_size, void* d_ws, size_t ws_size,
                              hipStream_t stream) {
    const float* x    = (const float*)d_in[0];
    const float* w    = (const float*)d_in[1];
    const float* bias = (const float*)d_in[2];
    const int*   em   = (const int*)d_in[3];
    float*       out  = (float*)d_out;

    snl_sparse4<<<dim3(N_ / G_), dim3(1024), 0, stream>>>(x, w, bias, em, out);
}